// Round 3
// baseline (730.322 us; speedup 1.0000x reference)
//
#include <hip/hip_runtime.h>
#include <hip/hip_bf16.h>
#include <cstdint>

// Problem constants (fixed-shape problem)
constexpr int NT   = 8192;
constexpr int H    = 1024;
constexpr int FFN  = 4096;
constexpr int E    = 8;
constexpr int M    = NT * 2;     // 16384 dispatched rows (topk=2)
constexpr int CAP  = M / E;      // 2048 rows per expert

typedef unsigned short u16;
typedef short short8 __attribute__((ext_vector_type(8)));
typedef float f32x4 __attribute__((ext_vector_type(4)));

// dispatched row -> source token (inverse of scatter_index); static device mem
// avoids betting on ws_size headroom.
__device__ int g_inv[M];

__device__ __forceinline__ u16 f2bf(float f) {
  union { float f; unsigned u; } c{f};
  unsigned r = (c.u + 0x7FFFu + ((c.u >> 16) & 1u)) >> 16;  // RNE
  return (u16)r;
}
// async global->LDS direct copy, 16B per lane. LDS dest = wave-uniform base + lane*16.
__device__ __forceinline__ void async16(const void* g, void* l) {
  auto gp = reinterpret_cast<const __attribute__((address_space(1))) unsigned*>(
      reinterpret_cast<uintptr_t>(g));
  auto lp = reinterpret_cast<__attribute__((address_space(3))) unsigned*>(
      reinterpret_cast<uintptr_t>(l));
  __builtin_amdgcn_global_load_lds(gp, lp, 16, 0, 0);
}

// ---------- transpose tile body: W [E][K][N] fp32 -> WT [E][N][K] bf16 ------
// 64x64 tile, fp32 LDS stride 65 (conflict-free), 16B loads + 16B stores.
__device__ __forceinline__ void transpose_body(const float* __restrict__ W,
                                               u16* __restrict__ WT,
                                               int K, int N, int tb,
                                               void* smem_) {
  float (*tile)[65] = (float(*)[65])smem_;
  const int ntx = N >> 6;
  const int per = ntx * (K >> 6);
  const int e   = tb / per;
  const int rem = tb - e * per;
  const int bx  = rem % ntx;
  const int by  = rem / ntx;
  const float* Wp = W + (size_t)e * K * N;
  u16* Tp = WT + (size_t)e * K * N;
  const int k0 = by * 64, n0 = bx * 64;
  const int tid = threadIdx.x;

  const int u = tid & 15, krb = tid >> 4;
#pragma unroll
  for (int p = 0; p < 4; ++p) {
    const int kr = p * 16 + krb;
    float4 v = *(const float4*)&Wp[(size_t)(k0 + kr) * N + n0 + u * 4];
    tile[kr][u * 4 + 0] = v.x;
    tile[kr][u * 4 + 1] = v.y;
    tile[kr][u * 4 + 2] = v.z;
    tile[kr][u * 4 + 3] = v.w;
  }
  __syncthreads();

  const int n = tid >> 3, cb = tid & 7;
#pragma unroll
  for (int p = 0; p < 2; ++p) {
    const int nn = p * 32 + n;
    u16 pack[8];
#pragma unroll
    for (int j = 0; j < 8; ++j) pack[j] = f2bf(tile[cb * 8 + j][nn]);
    *(short8*)&Tp[(size_t)(n0 + nn) * K + k0 + cb * 8] = *(short8*)pack;
  }
}

// ---------- pre-kernel: fused W0-transpose + scatter-cast + invperm + zero(out)
// blocks [0,8192): W0^T tiles; [8192,16384): scatter one token each;
// [16384,16448): inverse permutation; [16448,18496): zero 16KB of out each.
__global__ __launch_bounds__(256)
void pre_kernel(const float* __restrict__ x, const float* __restrict__ w0,
                const int* __restrict__ sidx, u16* __restrict__ wt0,
                u16* __restrict__ disp, float* __restrict__ outz) {
  __shared__ float tile[64][65];
  const int b = blockIdx.x;
  const int tid = threadIdx.x;
  if (b < 8192) {                       // W0 [E][H][FFN] -> wt0 [E][FFN][H]
    transpose_body(w0, wt0, H, FFN, b, tile);
    return;
  }
  if (b < 16384) {                      // scatter + fp32->bf16 cast
    const int t = b - 8192;
    const int r0 = sidx[2 * t + 0];
    const int r1 = sidx[2 * t + 1];
    float4 v = ((const float4*)(x + (size_t)t * H))[tid];
    ushort4 bb;
    bb.x = f2bf(v.x); bb.y = f2bf(v.y); bb.z = f2bf(v.z); bb.w = f2bf(v.w);
    ((ushort4*)disp)[(size_t)r0 * (H / 4) + tid] = bb;
    ((ushort4*)disp)[(size_t)r1 * (H / 4) + tid] = bb;
    return;
  }
  if (b < 16448) {                      // invperm
    const int i = (b - 16384) * 256 + tid;
    g_inv[sidx[i]] = i >> 1;
    return;
  }
  const int zb = b - 16448;             // zero out (atomic accum target)
  float4 z = {0.f, 0.f, 0.f, 0.f};
#pragma unroll
  for (int p = 0; p < 4; ++p)
    ((float4*)outz)[(size_t)zb * 1024 + p * 256 + tid] = z;
}

// ---------- GEMM: C[M,N] = A[M,K] * Bt[N,K]^T, bf16 in, 128x128 tile, BK=64 --
// XOR-swizzled LDS chunks (0 bank conflicts), expert = b&7 XCD pinning,
// 4x4 supertile order for L2. Optional fused transpose job (1 gemm : 2 transpose
// block interleave). ATOMIC epilogue: fp32 atomicAdd into out via g_inv.
template <bool GELU, bool ATOMIC>
__global__ __launch_bounds__(256)
void gemm_bt_kernel(const u16* __restrict__ A,   // [E][Mn][Kn]
                    const u16* __restrict__ Bt,  // [E][Nn][Kn]
                    u16* __restrict__ C,         // [E][Mn][Nn] (if !ATOMIC)
                    float* __restrict__ outp,    // [NT][H]     (if ATOMIC)
                    int Mn, int Nn, int Kn, int ny,
                    const float* __restrict__ Wx, u16* __restrict__ WTx,
                    int Kx, int Nx) {
  __shared__ __align__(16) char smem[32768];
  int b = blockIdx.x;
  if (Wx != nullptr) {   // fused transpose blocks: of every 3, blocks r=1,2
    const int g = b / 3, r = b - g * 3;
    if (r != 0) { transpose_body(Wx, WTx, Kx, Nx, g * 2 + (r - 1), smem); return; }
    b = g;
  }
  u16* lA = (u16*)smem;             // [128 rows][64 k] swizzled chunks, 16 KB
  u16* lB = (u16*)(smem + 16384);

  const int e = b & 7;                        // expert -> XCD pinning
  const int t = b >> 3;
  const int q = t & 15, s = t >> 4;
  const int sy = ny >> 2;
  const int sm = s % sy, sn = s / sy;
  const int tm = sm * 4 + (q & 3), tn = sn * 4 + (q >> 2);
  const int m0 = tm * 128, n0 = tn * 128;

  const u16* Ae = A  + (size_t)e * Mn * Kn + (size_t)m0 * Kn;
  const u16* Be = Bt + (size_t)e * Nn * Kn + (size_t)n0 * Kn;

  const int tid  = threadIdx.x;
  const int lane = tid & 63;
  const int wave = tid >> 6;
  const int wr = wave >> 1, wc = wave & 1;    // 2x2 wave grid, 64x64 each
  const int lhi = lane >> 4, llo = lane & 15;

  // staging: inst i covers rows [i*8,i*8+8); lane -> row i*8 + l/8, LDS slot
  // l%8; fetch global chunk (l%8)^(l/8) so frag reads are conflict-free.
  const int sr = lane >> 3;
  const int gc = (lane & 7) ^ sr;

  f32x4 acc[4][4] = {};

  for (int kt = 0; kt < Kn; kt += 64) {
#pragma unroll
    for (int s2 = 0; s2 < 4; ++s2) {
      const int i = wave * 4 + s2;
      const int row = i * 8 + sr;
      async16(Ae + (size_t)row * Kn + kt + gc * 8, &lA[i * 512]);
      async16(Be + (size_t)row * Kn + kt + gc * 8, &lB[i * 512]);
    }
    __syncthreads();

#pragma unroll
    for (int ks = 0; ks < 2; ++ks) {
      short8 af[4], bf[4];
#pragma unroll
      for (int i = 0; i < 4; ++i) {
        const int row = wr * 64 + i * 16 + llo;
        const int pc = (ks * 4 + lhi) ^ (llo & 7);
        af[i] = *(const short8*)&lA[row * 64 + pc * 8];
      }
#pragma unroll
      for (int j = 0; j < 4; ++j) {
        const int row = wc * 64 + j * 16 + llo;
        const int pc = (ks * 4 + lhi) ^ (llo & 7);
        bf[j] = *(const short8*)&lB[row * 64 + pc * 8];
      }
#pragma unroll
      for (int i = 0; i < 4; ++i)
#pragma unroll
        for (int j = 0; j < 4; ++j)
          acc[i][j] = __builtin_amdgcn_mfma_f32_16x16x32_bf16(af[i], bf[j], acc[i][j], 0, 0, 0);
    }
    __syncthreads();
  }

  // epilogue: C/D layout col=lane&15, row=(lane>>4)*4+reg  [m89-verified]
  if (!ATOMIC) {
    u16* Ce = C + (size_t)e * Mn * Nn;
#pragma unroll
    for (int i = 0; i < 4; ++i) {
      const int mrow = m0 + wr * 64 + i * 16 + lhi * 4;
#pragma unroll
      for (int j = 0; j < 4; ++j) {
        const int ncol = n0 + wc * 64 + j * 16 + llo;
#pragma unroll
        for (int r = 0; r < 4; ++r) {
          float v = acc[i][j][r];
          if (GELU) v = 0.5f * v * (1.0f + erff(v * 0.70710678118654752f));
          Ce[(size_t)(mrow + r) * Nn + ncol] = f2bf(v);
        }
      }
    }
  } else {
    const int grBase = e * Mn + m0 + wr * 64;   // global dispatched row base
#pragma unroll
    for (int i = 0; i < 4; ++i) {
      const int rb = grBase + i * 16 + lhi * 4;
#pragma unroll
      for (int r = 0; r < 4; ++r) {
        const int tok = g_inv[rb + r];
        float* orow = outp + (size_t)tok * H + n0 + wc * 64 + llo;
#pragma unroll
        for (int j = 0; j < 4; ++j)
          atomicAdd(orow + j * 16, acc[i][j][r]);
      }
    }
  }
}

// ---------- standalone transpose (serial fallback when ws is tight) ----------
__global__ __launch_bounds__(256)
void transpose_cvt_kernel(const float* __restrict__ W, u16* __restrict__ WT,
                          int K, int N) {
  __shared__ float tile[64][65];
  transpose_body(W, WT, K, N, blockIdx.x, tile);
}

extern "C" void kernel_launch(void* const* d_in, const int* in_sizes, int n_in,
                              void* d_out, int out_size, void* d_ws, size_t ws_size,
                              hipStream_t stream) {
  (void)in_sizes; (void)n_in; (void)out_size;
  const float* x    = (const float*)d_in[0];
  const float* w0   = (const float*)d_in[1];
  const float* w1   = (const float*)d_in[2];
  const int*   sidx = (const int*)d_in[3];
  float* out = (float*)d_out;

  // workspace layout:
  //   wt0 : W0^T bf16 [E][FFN][H]        64 MB   @ 0
  //   disp: dispatched bf16 [M][H]       32 MB   @ 64 MB
  //   mid : gelu(x@W0) bf16 [E][CAP][FFN]128 MB  @ 96 MB
  //   wt1 : W1^T bf16 [E][H][FFN]        64 MB   @ 224 MB (if ws allows;
  //         else aliases wt0 and transposes serially after GEMM0)
  char* ws = (char*)d_ws;
  const size_t MB = 1024ull * 1024;
  u16* wt0  = (u16*)ws;
  u16* disp = (u16*)(ws + 64 * MB);
  u16* mid  = (u16*)(ws + 96 * MB);
  const bool roomy = ws_size >= 288 * MB;
  u16* wt1 = roomy ? (u16*)(ws + 224 * MB) : wt0;

  // 1) fused: W0 transpose + scatter/cast + invperm + zero(out)
  pre_kernel<<<18496, 256, 0, stream>>>(x, w0, sidx, wt0, disp, out);

  // 2) mid = gelu(disp @ W0^T)  [+ fused W1 transpose when roomy]
  if (roomy) {
    gemm_bt_kernel<true, false><<<12288, 256, 0, stream>>>(
        disp, wt0, mid, nullptr, CAP, FFN, H, CAP / 128, w1, wt1, FFN, H);
  } else {
    gemm_bt_kernel<true, false><<<4096, 256, 0, stream>>>(
        disp, wt0, mid, nullptr, CAP, FFN, H, CAP / 128, nullptr, nullptr, 0, 0);
    transpose_cvt_kernel<<<8192, 256, 0, stream>>>(w1, wt1, FFN, H);
  }

  // 3) out += mid @ W1^T (atomic fp32 epilogue through g_inv; replaces
  //    ye materialization + gather kernel)
  gemm_bt_kernel<false, true><<<1024, 256, 0, stream>>>(
      mid, wt1, nullptr, out, CAP, H, FFN, CAP / 128, nullptr, nullptr, 0, 0);
}

// Round 4
// 689.899 us; speedup vs baseline: 1.0586x; 1.0586x over previous
//
#include <hip/hip_runtime.h>
#include <hip/hip_bf16.h>
#include <cstdint>

// Problem constants (fixed-shape problem)
constexpr int NT   = 8192;
constexpr int H    = 1024;
constexpr int FFN  = 4096;
constexpr int E    = 8;
constexpr int M    = NT * 2;     // 16384 dispatched rows (topk=2)
constexpr int CAP  = M / E;      // 2048 rows per expert

typedef unsigned short u16;
typedef short short8 __attribute__((ext_vector_type(8)));
typedef float f32x4 __attribute__((ext_vector_type(4)));

__device__ __forceinline__ u16 f2bf(float f) {
  union { float f; unsigned u; } c{f};
  unsigned r = (c.u + 0x7FFFu + ((c.u >> 16) & 1u)) >> 16;  // RNE
  return (u16)r;
}
__device__ __forceinline__ float bf2f(u16 u) {
  union { unsigned u; float f; } c{((unsigned)u) << 16};
  return c.f;
}
// async global->LDS direct copy, 16B per lane. LDS dest = wave-uniform base + lane*16.
__device__ __forceinline__ void async16(const void* g, void* l) {
  auto gp = reinterpret_cast<const __attribute__((address_space(1))) unsigned*>(
      reinterpret_cast<uintptr_t>(g));
  auto lp = reinterpret_cast<__attribute__((address_space(3))) unsigned*>(
      reinterpret_cast<uintptr_t>(l));
  __builtin_amdgcn_global_load_lds(gp, lp, 16, 0, 0);
}

// tanh-GELU via sigmoid identity: gelu(x) ~= x * sigmoid(2a(x + b x^3)).
// exp(-y) folded into exp2: coeffs pre-multiplied by log2(e).
__device__ __forceinline__ float gelu_fast(float x) {
  const float u = x * x;
  const float w = x * (-2.30220795f + -0.102943895f * u);  // -2a*log2e, -2ab*log2e
  return x * __frcp_rn(1.0f + exp2f(w));
}

// ---------- transpose tile body: W [E][K][N] fp32 -> WT [E][N][K] bf16 ------
// 64x64 tile, fp32 LDS stride 65 (conflict-free both phases), 16B ld + 16B st.
__device__ __forceinline__ void transpose_body(const float* __restrict__ W,
                                               u16* __restrict__ WT,
                                               int K, int N, int tb,
                                               float (*tile)[65]) {
  const int ntx = N >> 6;
  const int per = ntx * (K >> 6);
  const int e   = tb / per;
  const int rem = tb - e * per;
  const int bx  = rem % ntx;
  const int by  = rem / ntx;
  const float* Wp = W + (size_t)e * K * N;
  u16* Tp = WT + (size_t)e * K * N;
  const int k0 = by * 64, n0 = bx * 64;
  const int tid = threadIdx.x;

  const int u = tid & 15, krb = tid >> 4;
#pragma unroll
  for (int p = 0; p < 4; ++p) {
    const int kr = p * 16 + krb;
    float4 v = *(const float4*)&Wp[(size_t)(k0 + kr) * N + n0 + u * 4];
    tile[kr][u * 4 + 0] = v.x;
    tile[kr][u * 4 + 1] = v.y;
    tile[kr][u * 4 + 2] = v.z;
    tile[kr][u * 4 + 3] = v.w;
  }
  __syncthreads();

  const int n = tid >> 3, cb = tid & 7;
#pragma unroll
  for (int p = 0; p < 2; ++p) {
    const int nn = p * 32 + n;
    u16 pack[8];
#pragma unroll
    for (int j = 0; j < 8; ++j) pack[j] = f2bf(tile[cb * 8 + j][nn]);
    *(short8*)&Tp[(size_t)(n0 + nn) * K + k0 + cb * 8] = *(short8*)pack;
  }
}

// ---------- scatter body: 4 tokens per block, 16B stores ----------
__device__ __forceinline__ void scatter_body(const float* __restrict__ x,
                                             const int* __restrict__ sidx,
                                             u16* __restrict__ disp, int b) {
  const int tid = threadIdx.x;
  const int half = tid >> 7;      // 0,1: token select within pair
  const int r = tid & 127;        // covers 8 floats each
#pragma unroll
  for (int it = 0; it < 2; ++it) {
    const int t = it * 4096 + b * 2 + half;
    const int r0 = sidx[2 * t + 0];
    const int r1 = sidx[2 * t + 1];
    const float4* xr = (const float4*)(x + (size_t)t * H);
    float4 v0 = xr[r * 2 + 0];
    float4 v1 = xr[r * 2 + 1];
    u16 pk[8] = {f2bf(v0.x), f2bf(v0.y), f2bf(v0.z), f2bf(v0.w),
                 f2bf(v1.x), f2bf(v1.y), f2bf(v1.z), f2bf(v1.w)};
    *(short8*)&disp[(size_t)r0 * H + r * 8] = *(short8*)pk;
    *(short8*)&disp[(size_t)r1 * H + r * 8] = *(short8*)pk;
  }
}

// ---------- pre-kernel: scatter [0,2048) + W0^T [2048,10240) + W1^T rest ----
__global__ __launch_bounds__(256)
void pre_kernel(const float* __restrict__ x, const float* __restrict__ w0,
                const float* __restrict__ w1, const int* __restrict__ sidx,
                u16* __restrict__ wt0, u16* __restrict__ wt1,
                u16* __restrict__ disp) {
  __shared__ float tile[64][65];
  const int b = blockIdx.x;
  if (b < 2048) { scatter_body(x, sidx, disp, b); return; }
  if (b < 10240) { transpose_body(w0, wt0, H, FFN, b - 2048, tile); return; }
  transpose_body(w1, wt1, FFN, H, b - 10240, tile);
}

// ---------- standalone transpose (ws-tight fallback) ----------
__global__ __launch_bounds__(256)
void transpose_cvt_kernel(const float* __restrict__ W, u16* __restrict__ WT,
                          int K, int N) {
  __shared__ float tile[64][65];
  transpose_body(W, WT, K, N, blockIdx.x, tile);
}

// ---------- GEMM (round-2 config): C[M,N] = A[M,K]*Bt[N,K]^T, bf16 ----------
// 128x128 tile, BK=64, XOR-swizzled LDS chunks (0 conflicts),
// expert = b&7 XCD pinning, 4x4 supertile order for L2.
template <bool GELU>
__global__ __launch_bounds__(256)
void gemm_bt_kernel(const u16* __restrict__ A,   // [E][Mn][Kn]
                    const u16* __restrict__ Bt,  // [E][Nn][Kn]
                    u16* __restrict__ C,         // [E][Mn][Nn]
                    int Mn, int Nn, int Kn, int ny) {
  __shared__ __align__(16) u16 lA[128 * 64];
  __shared__ __align__(16) u16 lB[128 * 64];

  const int b = blockIdx.x;
  const int e = b & 7;
  const int t = b >> 3;
  const int q = t & 15, s = t >> 4;
  const int sy = ny >> 2;
  const int sm = s % sy, sn = s / sy;
  const int tm = sm * 4 + (q & 3), tn = sn * 4 + (q >> 2);
  const int m0 = tm * 128, n0 = tn * 128;

  const u16* Ae = A  + (size_t)e * Mn * Kn + (size_t)m0 * Kn;
  const u16* Be = Bt + (size_t)e * Nn * Kn + (size_t)n0 * Kn;
  u16* Ce = C + (size_t)e * Mn * Nn;

  const int tid  = threadIdx.x;
  const int lane = tid & 63;
  const int wave = tid >> 6;
  const int wr = wave >> 1, wc = wave & 1;
  const int lhi = lane >> 4, llo = lane & 15;

  const int sr = lane >> 3;
  const int gc = (lane & 7) ^ sr;   // swizzled global chunk

  f32x4 acc[4][4] = {};

  for (int kt = 0; kt < Kn; kt += 64) {
#pragma unroll
    for (int s2 = 0; s2 < 4; ++s2) {
      const int i = wave * 4 + s2;
      const int row = i * 8 + sr;
      async16(Ae + (size_t)row * Kn + kt + gc * 8, &lA[i * 512]);
      async16(Be + (size_t)row * Kn + kt + gc * 8, &lB[i * 512]);
    }
    __syncthreads();

#pragma unroll 1
    for (int ks = 0; ks < 2; ++ks) {
      short8 af[4], bf[4];
#pragma unroll
      for (int i = 0; i < 4; ++i) {
        const int row = wr * 64 + i * 16 + llo;
        const int pc = (ks * 4 + lhi) ^ (llo & 7);
        af[i] = *(const short8*)&lA[row * 64 + pc * 8];
      }
#pragma unroll
      for (int j = 0; j < 4; ++j) {
        const int row = wc * 64 + j * 16 + llo;
        const int pc = (ks * 4 + lhi) ^ (llo & 7);
        bf[j] = *(const short8*)&lB[row * 64 + pc * 8];
      }
#pragma unroll
      for (int i = 0; i < 4; ++i)
#pragma unroll
        for (int j = 0; j < 4; ++j)
          acc[i][j] = __builtin_amdgcn_mfma_f32_16x16x32_bf16(af[i], bf[j], acc[i][j], 0, 0, 0);
    }
    __syncthreads();
  }

  // epilogue: C/D layout col=lane&15, row=(lane>>4)*4+reg  [m89-verified]
#pragma unroll
  for (int i = 0; i < 4; ++i) {
    const int mrow = m0 + wr * 64 + i * 16 + lhi * 4;
#pragma unroll
    for (int j = 0; j < 4; ++j) {
      const int ncol = n0 + wc * 64 + j * 16 + llo;
#pragma unroll
      for (int r = 0; r < 4; ++r) {
        float v = acc[i][j][r];
        if (GELU) v = gelu_fast(v);
        Ce[(size_t)(mrow + r) * Nn + ncol] = f2bf(v);
      }
    }
  }
}

// ---------- gather + sum topk -> fp32 out; 16B loads, 4 tokens/block --------
__global__ __launch_bounds__(256)
void gather_sum_kernel(const u16* __restrict__ ye,
                       const int* __restrict__ sidx,
                       float* __restrict__ out) {
  const int tid = threadIdx.x;
  const int half = tid >> 7;
  const int r = tid & 127;
#pragma unroll
  for (int it = 0; it < 2; ++it) {
    const int t = it * 4096 + blockIdx.x * 2 + half;
    const int r0 = sidx[2 * t + 0];
    const int r1 = sidx[2 * t + 1];
    short8 a = *(const short8*)&ye[(size_t)r0 * H + r * 8];
    short8 b = *(const short8*)&ye[(size_t)r1 * H + r * 8];
    float4 s0, s1;
    s0.x = bf2f((u16)a[0]) + bf2f((u16)b[0]);
    s0.y = bf2f((u16)a[1]) + bf2f((u16)b[1]);
    s0.z = bf2f((u16)a[2]) + bf2f((u16)b[2]);
    s0.w = bf2f((u16)a[3]) + bf2f((u16)b[3]);
    s1.x = bf2f((u16)a[4]) + bf2f((u16)b[4]);
    s1.y = bf2f((u16)a[5]) + bf2f((u16)b[5]);
    s1.z = bf2f((u16)a[6]) + bf2f((u16)b[6]);
    s1.w = bf2f((u16)a[7]) + bf2f((u16)b[7]);
    float4* orow = (float4*)(out + (size_t)t * H);
    orow[r * 2 + 0] = s0;
    orow[r * 2 + 1] = s1;
  }
}

extern "C" void kernel_launch(void* const* d_in, const int* in_sizes, int n_in,
                              void* d_out, int out_size, void* d_ws, size_t ws_size,
                              hipStream_t stream) {
  (void)in_sizes; (void)n_in; (void)out_size;
  const float* x    = (const float*)d_in[0];
  const float* w0   = (const float*)d_in[1];
  const float* w1   = (const float*)d_in[2];
  const int*   sidx = (const int*)d_in[3];
  float* out = (float*)d_out;

  // workspace layout (288 MB; round-3 behavior confirmed ws_size >= 288MB):
  //   wt0 : W0^T bf16 [E][FFN][H]          64 MB @ 0
  //   wt1 : W1^T bf16 [E][H][FFN]          64 MB @ 64 MB
  //   disp: dispatched bf16 [M][H]         32 MB @ 128 MB (aliased as ye)
  //   mid : gelu(x@W0) bf16 [E][CAP][FFN] 128 MB @ 160 MB
  char* ws = (char*)d_ws;
  const size_t MB = 1024ull * 1024;
  u16* wt0  = (u16*)ws;
  u16* wt1  = (u16*)(ws + 64 * MB);
  u16* disp = (u16*)(ws + 128 * MB);
  u16* mid  = (u16*)(ws + 160 * MB);
  u16* ye   = disp;  // disp dead after gemm0
  const bool roomy = ws_size >= 288 * MB;

  if (roomy) {
    // 1) fused: scatter/cast + W0^T + W1^T
    pre_kernel<<<18432, 256, 0, stream>>>(x, w0, w1, sidx, wt0, wt1, disp);
    // 2) mid = gelu(disp @ W0^T)
    gemm_bt_kernel<true><<<4096, 256, 0, stream>>>(disp, wt0, mid, CAP, FFN, H, CAP / 128);
    // 3) ye = mid @ W1^T
    gemm_bt_kernel<false><<<1024, 256, 0, stream>>>(mid, wt1, ye, CAP, H, FFN, CAP / 128);
  } else {
    // tight ws: wt1 aliases wt0, transpose W1 after gemm0
    wt1 = wt0;
    pre_kernel<<<10240, 256, 0, stream>>>(x, w0, w1, sidx, wt0, wt1, disp);
    gemm_bt_kernel<true><<<4096, 256, 0, stream>>>(disp, wt0, mid, CAP, FFN, H, CAP / 128);
    transpose_cvt_kernel<<<8192, 256, 0, stream>>>(w1, wt1, FFN, H);
    gemm_bt_kernel<false><<<1024, 256, 0, stream>>>(mid, wt1, ye, CAP, H, FFN, CAP / 128);
  }
  // 4) out[t] = ye[s0] + ye[s1]
  gather_sum_kernel<<<2048, 256, 0, stream>>>(ye, sidx, out);
}